// Round 1
// baseline (73.486 us; speedup 1.0000x reference)
//
#include <hip/hip_runtime.h>
#include <math.h>

#define NP 8192
#define SEQ 4
#define KNN 16
#define R2 1.0f

// One wave (64 lanes) per query point. Block = 256 threads = 4 waves.
// Scans candidates 256 at a time (4/lane) in ascending index order,
// collects first 16 in-radius indices via ballot-mask bit extraction,
// then computes the 4-seq neighbor-distance sum in the same wave.
__global__ __launch_bounds__(256, 8) void ballq_fused(
    const float* __restrict__ xyz,   // [NP,3]
    const float* __restrict__ pf,    // [SEQ,NP,3]
    float* __restrict__ partial)     // [gridDim.x]
{
    const int lane = threadIdx.x & 63;
    const int wv   = threadIdx.x >> 6;
    const int i    = (blockIdx.x << 2) + wv;   // query point

    const float xi = xyz[3 * i + 0];
    const float yi = xyz[3 * i + 1];
    const float zi = xyz[3 * i + 2];

    int myNbr = -1;   // neighbor index owned by lane c (c-th hit), lanes 0..15
    int cnt   = 0;    // wave-uniform hit count
    int first = -1;   // wave-uniform first hit (for padding)

    for (int base = 0; base < NP; base += 256) {
        unsigned long long masks[4];
#pragma unroll
        for (int u = 0; u < 4; ++u) {
            const int j = base + (u << 6) + lane;
            const float dx = xyz[3 * j + 0] - xi;
            const float dy = xyz[3 * j + 1] - yi;
            const float dz = xyz[3 * j + 2] - zi;
            masks[u] = __ballot(dx * dx + dy * dy + dz * dz < R2);
        }
#pragma unroll
        for (int u = 0; u < 4; ++u) {
            unsigned long long m = masks[u];
            const int sub = base + (u << 6);
            while (m && cnt < KNN) {             // wave-uniform loop
                const int b = __builtin_ctzll(m);
                const int j = sub + b;
                if (cnt == 0) first = j;
                if (lane == cnt) myNbr = j;      // lane c takes hit c
                ++cnt;
                m &= m - 1;
            }
        }
        if (cnt >= KNN) break;                   // wave-uniform early exit
    }
    if (myNbr < 0) myNbr = first;                // pad lanes [cnt,16) with first hit

    // Phase 2: lane = k + 16*s -> one (seq s, neighbor k) distance term.
    const int k = lane & 15;
    const int s = lane >> 4;
    const int j = __shfl(myNbr, k);
    const size_t oi = ((size_t)s * NP + i) * 3;
    const size_t oj = ((size_t)s * NP + j) * 3;
    const float dx = pf[oi + 0] - pf[oj + 0];
    const float dy = pf[oi + 1] - pf[oj + 1];
    const float dz = pf[oi + 2] - pf[oj + 2];
    float d = sqrtf(fmaxf(dx * dx + dy * dy + dz * dz, 1e-24f));

    // 64-lane reduction
#pragma unroll
    for (int off = 32; off > 0; off >>= 1) d += __shfl_xor(d, off);

    __shared__ float sacc[4];
    if (lane == 0) sacc[wv] = d;
    __syncthreads();
    if (threadIdx.x == 0)
        partial[blockIdx.x] = sacc[0] + sacc[1] + sacc[2] + sacc[3];
}

__global__ __launch_bounds__(256) void ballq_reduce(
    const float* __restrict__ partial, int n, float* __restrict__ out)
{
    float s = 0.0f;
    for (int i = threadIdx.x; i < n; i += 256) s += partial[i];
#pragma unroll
    for (int off = 32; off > 0; off >>= 1) s += __shfl_xor(s, off);
    __shared__ float w[4];
    const int lane = threadIdx.x & 63, wv = threadIdx.x >> 6;
    if (lane == 0) w[wv] = s;
    __syncthreads();
    if (threadIdx.x == 0)
        out[0] = (w[0] + w[1] + w[2] + w[3]) * (1.0f / (float)(SEQ * NP * KNN));
}

extern "C" void kernel_launch(void* const* d_in, const int* in_sizes, int n_in,
                              void* d_out, int out_size, void* d_ws, size_t ws_size,
                              hipStream_t stream) {
    const float* xyz = (const float*)d_in[0];  // pc_source [1,8192,3]
    const float* pf  = (const float*)d_in[1];  // pred_flow [4,8192,3]
    float* partial   = (float*)d_ws;           // 2048 floats
    float* out       = (float*)d_out;

    const int nblocks = NP / 4;                // 4 waves/block, 1 point/wave
    ballq_fused<<<nblocks, 256, 0, stream>>>(xyz, pf, partial);
    ballq_reduce<<<1, 256, 0, stream>>>(partial, nblocks, out);
}